// Round 3
// baseline (257.926 us; speedup 1.0000x reference)
//
#include <hip/hip_runtime.h>
#include <hip/hip_bf16.h>

// GAT layer: N=4096, F_IN=128, F_OUT=64, HEADS=4.
// R3: A packed to a 2 MB bitmask (ballot kernel) -> gat_main reads masks from
//     registers (16B per 4 steps, L1-resident) instead of 64 MB of int32 with
//     16KB-stride multi-segment loads; d staged in LDS (broadcast reads).
// Kernels: zero_f4 -> pack_bits -> gat_prep -> gat_main -> gat_fin.

#define NN 4096
#define FIN 128
#define FOUT 64
#define NH 4

typedef __attribute__((ext_vector_type(8))) short bf16x8;
typedef __attribute__((ext_vector_type(4))) float f32x4;

__device__ __forceinline__ unsigned short f32_bf16(float f) {
    unsigned u = __builtin_bit_cast(unsigned, f);
    u += 0x7fffu + ((u >> 16) & 1u);          // round-to-nearest-even
    return (unsigned short)(u >> 16);
}

// ---------------- Kernel 0: zero the accumulation workspace ----------------
__global__ __launch_bounds__(256) void zero_f4(float4* __restrict__ p, int n4) {
    int i = blockIdx.x * 256 + threadIdx.x;
    if (i < n4) p[i] = make_float4(0.f, 0.f, 0.f, 0.f);
}

// ---------------- Kernel 0b: pack A (int32 0/1) into bitmask ----------------
// Abits[row][w] bit j = (A[row][w*64+j] > 0). 64 MB -> 2 MB.
__global__ __launch_bounds__(256) void pack_bits(
    const int* __restrict__ A, unsigned long long* __restrict__ Abits)
{
    const int b    = blockIdx.x;             // 65536 blocks
    const int row  = b >> 4;
    const int c0   = (b & 15) * 256;
    const int lane = threadIdx.x & 63;
    const int wv   = threadIdx.x >> 6;
    const int col  = c0 + wv * 64 + lane;
    unsigned long long m = __ballot(A[(size_t)row * NN + col] > 0);
    if (lane == 0) Abits[(size_t)row * 64 + (c0 >> 6) + wv] = m;
}

// ---------------- Kernel 1: prep ----------------
// H = X@W[h]^T + b (fp32). Outputs: bf16 H^T [h][o][n] (MFMA B-operand),
// fp32 Hrow [h][n][o] (diagonal term), s[h][n], d[h][n].
__global__ __launch_bounds__(256) void gat_prep(
    const float* __restrict__ X, const float* __restrict__ W,
    const float* __restrict__ b, const float* __restrict__ att,
    unsigned short* __restrict__ HbfT, float* __restrict__ Hrow,
    float* __restrict__ s_out, float* __restrict__ d_out)
{
    const int rb = blockIdx.x;           // 0..127
    const int h  = blockIdx.y;           // 0..3
    const int n0 = rb * 32;
    const int t  = threadIdx.x;          // 0..255

    __shared__ float Xl[32][132];
    __shared__ float Wt[128][68];

    for (int g = t; g < 32 * 32; g += 256) {
        int row = g >> 5, c4 = g & 31;
        float4 v = *(const float4*)&X[(size_t)(n0 + row) * FIN + c4 * 4];
        *(float4*)&Xl[row][c4 * 4] = v;
    }
    for (int g = t; g < 64 * 32; g += 256) {
        int o = g >> 5, c4 = g & 31;
        float4 v = *(const float4*)&W[((size_t)h * FOUT + o) * FIN + c4 * 4];
        Wt[c4 * 4 + 0][o] = v.x; Wt[c4 * 4 + 1][o] = v.y;
        Wt[c4 * 4 + 2][o] = v.z; Wt[c4 * 4 + 3][o] = v.w;
    }
    __syncthreads();

    const int rg = t >> 4;               // rows rg*2 .. rg*2+1
    const int og = t & 15;               // cols og*4 .. og*4+3
    float acc[2][4] = {};

    #pragma unroll 4
    for (int f4 = 0; f4 < 32; ++f4) {
        float xv[2][4], wv[4][4];
        #pragma unroll
        for (int i = 0; i < 2; ++i) {
            float4 tmp = *(const float4*)&Xl[rg * 2 + i][f4 * 4];
            xv[i][0] = tmp.x; xv[i][1] = tmp.y; xv[i][2] = tmp.z; xv[i][3] = tmp.w;
        }
        #pragma unroll
        for (int k = 0; k < 4; ++k) {
            float4 tmp = *(const float4*)&Wt[f4 * 4 + k][og * 4];
            wv[k][0] = tmp.x; wv[k][1] = tmp.y; wv[k][2] = tmp.z; wv[k][3] = tmp.w;
        }
        #pragma unroll
        for (int i = 0; i < 2; ++i)
            #pragma unroll
            for (int k = 0; k < 4; ++k)
                #pragma unroll
                for (int jj = 0; jj < 4; ++jj)
                    acc[i][jj] = fmaf(xv[i][k], wv[k][jj], acc[i][jj]);
    }

    float bb[4], as_[4], ad_[4];
    #pragma unroll
    for (int jj = 0; jj < 4; ++jj) {
        bb[jj]  = b[h * FOUT + og * 4 + jj];
        as_[jj] = att[h * 2 * FOUT + og * 4 + jj];
        ad_[jj] = att[h * 2 * FOUT + FOUT + og * 4 + jj];
    }
    #pragma unroll
    for (int i = 0; i < 2; ++i)
        #pragma unroll
        for (int jj = 0; jj < 4; ++jj)
            acc[i][jj] += bb[jj];

    float sp[2] = {0.f, 0.f}, dp[2] = {0.f, 0.f};
    #pragma unroll
    for (int i = 0; i < 2; ++i)
        #pragma unroll
        for (int jj = 0; jj < 4; ++jj) {
            sp[i] = fmaf(acc[i][jj], as_[jj], sp[i]);
            dp[i] = fmaf(acc[i][jj], ad_[jj], dp[i]);
        }
    #pragma unroll
    for (int off = 1; off < 16; off <<= 1) {
        #pragma unroll
        for (int i = 0; i < 2; ++i) {
            sp[i] += __shfl_xor(sp[i], off);
            dp[i] += __shfl_xor(dp[i], off);
        }
    }
    if (og == 0) {
        #pragma unroll
        for (int i = 0; i < 2; ++i) {
            int nn = n0 + rg * 2 + i;
            s_out[h * NN + nn] = sp[i];
            d_out[h * NN + nn] = dp[i];
        }
    }

    #pragma unroll
    for (int i = 0; i < 2; ++i) {
        float4 v = make_float4(acc[i][0], acc[i][1], acc[i][2], acc[i][3]);
        *(float4*)&Hrow[((size_t)h * NN + n0 + rg * 2 + i) * FOUT + og * 4] = v;
    }
    #pragma unroll
    for (int jj = 0; jj < 4; ++jj) {
        int o = og * 4 + jj;
        ushort2 p;
        p.x = f32_bf16(acc[0][jj]);
        p.y = f32_bf16(acc[1][jj]);
        *(ushort2*)&HbfT[((size_t)h * FOUT + o) * NN + n0 + rg * 2] = p;
    }
}

// ---------------- Kernel 2: masked softmax-aggregate (K-split partials) ------
// grid (256 row-tiles, 4 K-splits), 512 threads = 8 waves = 4 heads x 2 subchunks.
__global__ __launch_bounds__(512, 8) void gat_main(
    const unsigned* __restrict__ Abits, const unsigned short* __restrict__ HbfT,
    const float* __restrict__ s_g, const float* __restrict__ d_g,
    float* __restrict__ Hacc, float* __restrict__ lpart)
{
    const int n0   = blockIdx.x * 16;
    const int by   = blockIdx.y;         // K split 0..3 -> cols [by*1024, +1024)
    const int tid  = threadIdx.x;
    const int wv   = tid >> 6;           // 0..7
    const int h    = wv & 3;
    const int sub  = wv >> 2;            // sub-chunk of 512 cols
    const int lane = tid & 63;
    const int r    = lane & 15;          // A-operand row / B-operand col
    const int q    = lane >> 4;          // quad -> k offset q*8

    __shared__ float out_acc[4][16][64]; // 16 KB
    __shared__ float d_lds[8][512];      // 16 KB: per-wave-slot d subchunk
    __shared__ float l_lds[8][16];

    for (int g = tid; g < 4 * 16 * 64; g += 512) ((float*)out_acc)[g] = 0.0f;
    // stage d: wave slot wg = (sub_g<<2)|h_g covers d[h_g][by*1024+sub_g*512 ..+512)
    for (int g = tid; g < 8 * 512; g += 512) {
        int wg = g >> 9, col = g & 511;
        int hg = wg & 3, sg = wg >> 2;
        d_lds[wg][col] = d_g[hg * NN + by * 1024 + sg * 512 + col];
    }
    __syncthreads();

    const int n = n0 + r;
    const float s_h = s_g[h * NN + n];
    const unsigned short* hb_base = HbfT + ((size_t)h * FOUT + r) * NN;
    // bit dwords for row n, this wave's 512-col subchunk: dword s = cols [c0+s*32, +32)
    const unsigned* abrow = Abits + (size_t)n * 128 + by * 32 + sub * 16;
    const int c0 = by * 1024 + sub * 512;

    f32x4 acc0 = {0,0,0,0}, acc1 = {0,0,0,0}, acc2 = {0,0,0,0}, acc3 = {0,0,0,0};
    float l_part = 0.f;
    const int qs = q * 8;

    for (int g4 = 0; g4 < 4; ++g4) {
        // masks for steps g4*4 .. g4*4+3 (16B, L1-resident: 16 rows x 64B)
        const uint4 ab = *(const uint4*)(abrow + g4 * 4);
        const unsigned abw[4] = {ab.x, ab.y, ab.z, ab.w};

        #pragma unroll
        for (int s2 = 0; s2 < 4; ++s2) {
            const int step = g4 * 4 + s2;
            const int mkl  = step * 32 + qs;      // LDS-local col offset
            const unsigned bits = abw[s2] >> qs;  // 8 mask bits for this lane

            const float4 dd0 = *(const float4*)&d_lds[wv][mkl];
            const float4 dd1 = *(const float4*)&d_lds[wv][mkl + 4];
            float dv[8] = {dd0.x, dd0.y, dd0.z, dd0.w, dd1.x, dd1.y, dd1.z, dd1.w};

            bf16x8 af;
            float lsum = 0.f;
            #pragma unroll
            for (int j = 0; j < 8; ++j) {
                float tt = s_h + dv[j];
                float lr = fmaxf(tt, 0.01f * tt);   // leaky_relu
                float e  = __expf(lr);
                float w  = (bits & (1u << j)) ? e : 0.0f;
                lsum += w;
                af[j] = (short)f32_bf16(w);
            }
            l_part += lsum;

            const unsigned short* hb = hb_base + c0 + step * 32 + qs;
            bf16x8 b0 = *(const bf16x8*)(hb);
            bf16x8 b1 = *(const bf16x8*)(hb + 16 * NN);
            bf16x8 b2 = *(const bf16x8*)(hb + 32 * NN);
            bf16x8 b3 = *(const bf16x8*)(hb + 48 * NN);
            acc0 = __builtin_amdgcn_mfma_f32_16x16x32_bf16(af, b0, acc0, 0, 0, 0);
            acc1 = __builtin_amdgcn_mfma_f32_16x16x32_bf16(af, b1, acc1, 0, 0, 0);
            acc2 = __builtin_amdgcn_mfma_f32_16x16x32_bf16(af, b2, acc2, 0, 0, 0);
            acc3 = __builtin_amdgcn_mfma_f32_16x16x32_bf16(af, b3, acc3, 0, 0, 0);
        }
    }

    // denominator partial: reduce across quads + sub-waves, then one atomic
    l_part += __shfl_xor(l_part, 16);
    l_part += __shfl_xor(l_part, 32);
    if (lane < 16) l_lds[wv][r] = l_part;
    __syncthreads();
    if (wv < 4 && lane < 16)
        atomicAdd(&lpart[h * NN + n0 + lane], l_lds[h][lane] + l_lds[h + 4][lane]);

    // merge the 2 sub-waves per head in LDS (unnormalized)
    #pragma unroll
    for (int reg = 0; reg < 4; ++reg) {
        int rr = q * 4 + reg;
        atomicAdd(&out_acc[h][rr][ 0 + r], acc0[reg]);
        atomicAdd(&out_acc[h][rr][16 + r], acc1[reg]);
        atomicAdd(&out_acc[h][rr][32 + r], acc2[reg]);
        atomicAdd(&out_acc[h][rr][48 + r], acc3[reg]);
    }
    __syncthreads();

    // block -> global partial accumulation (coalesced dword atomics)
    #pragma unroll
    for (int i = 0; i < 8; ++i) {
        int idx = i * 512 + tid;
        int hh = idx >> 10;
        int rr = (idx >> 6) & 15;
        int oo = idx & 63;
        atomicAdd(&Hacc[((size_t)hh * NN + n0 + rr) * FOUT + oo],
                  out_acc[hh][rr][oo]);
    }
}

// ---------------- Kernel 3: finalize ----------------
// out[n][o] = sum_h (Hacc[h][n][o] + w_diag*Hrow[h][n][o]) * 0.25/(l[h][n]+w_diag)
__global__ __launch_bounds__(256) void gat_fin(
    const float* __restrict__ Hacc, const float* __restrict__ Hrow,
    const float* __restrict__ lpart, const float* __restrict__ s_g,
    const float* __restrict__ d_g, float* __restrict__ out)
{
    const int tid = threadIdx.x;
    const int rr  = tid >> 4;
    const int c4  = tid & 15;
    const int n   = blockIdx.x * 16 + rr;
    const int o   = c4 * 4;

    float4 res = make_float4(0.f, 0.f, 0.f, 0.f);
    #pragma unroll
    for (int h = 0; h < NH; ++h) {
        float l  = lpart[h * NN + n];
        float tt = s_g[h * NN + n] + d_g[h * NN + n];
        float wd = __expf(fmaxf(tt, 0.01f * tt));
        float inv = 0.25f / (l + wd);
        float4 ha = *(const float4*)&Hacc[((size_t)h * NN + n) * FOUT + o];
        float4 hr = *(const float4*)&Hrow[((size_t)h * NN + n) * FOUT + o];
        res.x += (ha.x + wd * hr.x) * inv;
        res.y += (ha.y + wd * hr.y) * inv;
        res.z += (ha.z + wd * hr.z) * inv;
        res.w += (ha.w + wd * hr.w) * inv;
    }
    *(float4*)&out[(size_t)n * FOUT + o] = res;
}

extern "C" void kernel_launch(void* const* d_in, const int* in_sizes, int n_in,
                              void* d_out, int out_size, void* d_ws, size_t ws_size,
                              hipStream_t stream) {
    const float* X   = (const float*)d_in[0];
    const int*   A   = (const int*)  d_in[1];
    const float* W   = (const float*)d_in[2];
    const float* b   = (const float*)d_in[3];
    const float* att = (const float*)d_in[4];
    float* out = (float*)d_out;

    char* ws = (char*)d_ws;
    unsigned short* HbfT = (unsigned short*)ws;                    // 2 MB
    size_t off = (size_t)NH * FOUT * NN * 2;
    float* s_buf = (float*)(ws + off);  off += (size_t)NH * NN * 4;        // 64 KB
    float* d_buf = (float*)(ws + off);  off += (size_t)NH * NN * 4;        // 64 KB
    float* Hacc  = (float*)(ws + off);  off += (size_t)NH * NN * FOUT * 4; // 4 MB
    float* lpart = (float*)(ws + off);  off += (size_t)NH * NN * 4;        // 64 KB
    float* Hrow  = (float*)(ws + off);  off += (size_t)NH * NN * FOUT * 4; // 4 MB
    unsigned long long* Abits = (unsigned long long*)(ws + off);
    off += (size_t)NN * 64 * 8;                                            // 2 MB

    const int n4 = (NH * NN * FOUT + NH * NN) / 4;     // zero Hacc+lpart (contiguous)
    zero_f4<<<(n4 + 255) / 256, 256, 0, stream>>>((float4*)Hacc, n4);
    pack_bits<<<NN * 16, 256, 0, stream>>>(A, Abits);
    gat_prep<<<dim3(128, 4), 256, 0, stream>>>(X, W, b, att, HbfT, Hrow, s_buf, d_buf);
    gat_main<<<dim3(256, 4), 512, 0, stream>>>((const unsigned*)Abits, HbfT,
                                               s_buf, d_buf, Hacc, lpart);
    gat_fin<<<256, 256, 0, stream>>>(Hacc, Hrow, lpart, s_buf, d_buf, out);
}

// Round 5
// 195.830 us; speedup vs baseline: 1.3171x; 1.3171x over previous
//
#include <hip/hip_runtime.h>
#include <hip/hip_bf16.h>

// GAT layer: N=4096, F_IN=128, F_OUT=64, HEADS=4.
// R5 (= R4 with compile fix): gat_main block = 2 heads x 128 rows x 256 cols.
//  - H column-chunk staged ONCE into LDS (64 KB, XOR-swizzled 16B blocks) ->
//    B-fragments come from ds_read_b128 instead of 16-way divergent global gather.
//  - exp(leaky_relu(s+d)) = max(es_n*ed_m, es2_n*ed2_m) with es=e^s, es2=e^{0.01s}
//    precomputed per node -> hot loop has NO transcendentals; manual bf16 pack
//    (fix: __hip_bfloat162 is not trivially copyable -> no __builtin_bit_cast).
//  - row-sum l computed by a 5th MFMA with B = ones (quantization-consistent).
// Kernels: zero_f4 -> pack_bits -> gat_prep -> gat_main -> gat_fin.

#define NN 4096
#define FIN 128
#define FOUT 64
#define NH 4

typedef __attribute__((ext_vector_type(8))) short bf16x8;
typedef __attribute__((ext_vector_type(4))) float f32x4;
typedef __attribute__((ext_vector_type(4))) unsigned int u32x4;

__device__ __forceinline__ unsigned short f32_bf16(float f) {
    unsigned u = __builtin_bit_cast(unsigned, f);
    u += 0x7fffu + ((u >> 16) & 1u);          // round-to-nearest-even
    return (unsigned short)(u >> 16);
}

// ---------------- Kernel 0: zero the accumulation workspace ----------------
__global__ __launch_bounds__(256) void zero_f4(float4* __restrict__ p, int n4) {
    int i = blockIdx.x * 256 + threadIdx.x;
    if (i < n4) p[i] = make_float4(0.f, 0.f, 0.f, 0.f);
}

// ---------------- Kernel 0b: pack A (int32 0/1) into bitmask ----------------
__global__ __launch_bounds__(256) void pack_bits(
    const int* __restrict__ A, unsigned long long* __restrict__ Abits)
{
    const int b    = blockIdx.x;             // 65536 blocks
    const int row  = b >> 4;
    const int c0   = (b & 15) * 256;
    const int lane = threadIdx.x & 63;
    const int wv   = threadIdx.x >> 6;
    const int col  = c0 + wv * 64 + lane;
    unsigned long long m = __ballot(A[(size_t)row * NN + col] > 0);
    if (lane == 0) Abits[(size_t)row * 64 + (c0 >> 6) + wv] = m;
}

// ---------------- Kernel 1: prep ----------------
// H = X@W[h]^T + b (fp32). Outputs: bf16 H^T [h][o][n], fp32 Hrow [h][n][o],
// s,d and the factored exponentials es=e^s, es2=e^{0.01s}, ed=e^d, ed2=e^{0.01d}.
__global__ __launch_bounds__(256) void gat_prep(
    const float* __restrict__ X, const float* __restrict__ W,
    const float* __restrict__ b, const float* __restrict__ att,
    unsigned short* __restrict__ HbfT, float* __restrict__ Hrow,
    float* __restrict__ s_out, float* __restrict__ d_out,
    float* __restrict__ es_g, float* __restrict__ es2_g,
    float* __restrict__ ed_g, float* __restrict__ ed2_g)
{
    const int rb = blockIdx.x;           // 0..127
    const int h  = blockIdx.y;           // 0..3
    const int n0 = rb * 32;
    const int t  = threadIdx.x;          // 0..255

    __shared__ float Xl[32][132];
    __shared__ float Wt[128][68];

    for (int g = t; g < 32 * 32; g += 256) {
        int row = g >> 5, c4 = g & 31;
        float4 v = *(const float4*)&X[(size_t)(n0 + row) * FIN + c4 * 4];
        *(float4*)&Xl[row][c4 * 4] = v;
    }
    for (int g = t; g < 64 * 32; g += 256) {
        int o = g >> 5, c4 = g & 31;
        float4 v = *(const float4*)&W[((size_t)h * FOUT + o) * FIN + c4 * 4];
        Wt[c4 * 4 + 0][o] = v.x; Wt[c4 * 4 + 1][o] = v.y;
        Wt[c4 * 4 + 2][o] = v.z; Wt[c4 * 4 + 3][o] = v.w;
    }
    __syncthreads();

    const int rg = t >> 4;               // rows rg*2 .. rg*2+1
    const int og = t & 15;               // cols og*4 .. og*4+3
    float acc[2][4] = {};

    #pragma unroll 4
    for (int f4 = 0; f4 < 32; ++f4) {
        float xv[2][4], wv[4][4];
        #pragma unroll
        for (int i = 0; i < 2; ++i) {
            float4 tmp = *(const float4*)&Xl[rg * 2 + i][f4 * 4];
            xv[i][0] = tmp.x; xv[i][1] = tmp.y; xv[i][2] = tmp.z; xv[i][3] = tmp.w;
        }
        #pragma unroll
        for (int k = 0; k < 4; ++k) {
            float4 tmp = *(const float4*)&Wt[f4 * 4 + k][og * 4];
            wv[k][0] = tmp.x; wv[k][1] = tmp.y; wv[k][2] = tmp.z; wv[k][3] = tmp.w;
        }
        #pragma unroll
        for (int i = 0; i < 2; ++i)
            #pragma unroll
            for (int k = 0; k < 4; ++k)
                #pragma unroll
                for (int jj = 0; jj < 4; ++jj)
                    acc[i][jj] = fmaf(xv[i][k], wv[k][jj], acc[i][jj]);
    }

    float bb[4], as_[4], ad_[4];
    #pragma unroll
    for (int jj = 0; jj < 4; ++jj) {
        bb[jj]  = b[h * FOUT + og * 4 + jj];
        as_[jj] = att[h * 2 * FOUT + og * 4 + jj];
        ad_[jj] = att[h * 2 * FOUT + FOUT + og * 4 + jj];
    }
    #pragma unroll
    for (int i = 0; i < 2; ++i)
        #pragma unroll
        for (int jj = 0; jj < 4; ++jj)
            acc[i][jj] += bb[jj];

    float sp[2] = {0.f, 0.f}, dp[2] = {0.f, 0.f};
    #pragma unroll
    for (int i = 0; i < 2; ++i)
        #pragma unroll
        for (int jj = 0; jj < 4; ++jj) {
            sp[i] = fmaf(acc[i][jj], as_[jj], sp[i]);
            dp[i] = fmaf(acc[i][jj], ad_[jj], dp[i]);
        }
    #pragma unroll
    for (int off = 1; off < 16; off <<= 1) {
        #pragma unroll
        for (int i = 0; i < 2; ++i) {
            sp[i] += __shfl_xor(sp[i], off);
            dp[i] += __shfl_xor(dp[i], off);
        }
    }
    if (og == 0) {
        #pragma unroll
        for (int i = 0; i < 2; ++i) {
            int nn = n0 + rg * 2 + i;
            s_out[h * NN + nn]  = sp[i];
            d_out[h * NN + nn]  = dp[i];
            es_g [h * NN + nn]  = __expf(sp[i]);
            es2_g[h * NN + nn]  = __expf(0.01f * sp[i]);
            ed_g [h * NN + nn]  = __expf(dp[i]);
            ed2_g[h * NN + nn]  = __expf(0.01f * dp[i]);
        }
    }

    #pragma unroll
    for (int i = 0; i < 2; ++i) {
        float4 v = make_float4(acc[i][0], acc[i][1], acc[i][2], acc[i][3]);
        *(float4*)&Hrow[((size_t)h * NN + n0 + rg * 2 + i) * FOUT + og * 4] = v;
    }
    #pragma unroll
    for (int jj = 0; jj < 4; ++jj) {
        int o = og * 4 + jj;
        ushort2 p;
        p.x = f32_bf16(acc[0][jj]);
        p.y = f32_bf16(acc[1][jj]);
        *(ushort2*)&HbfT[((size_t)h * FOUT + o) * NN + n0 + rg * 2] = p;
    }
}

// ---------------- Kernel 2: masked softmax-aggregate ------------------------
// grid (32 row-tiles, 16 col-splits, 2 head-groups), 512 threads = 8 waves.
// wave w: rows n0+w*16..+16, loops over its 2 heads; K-loop over 256 cols.
__global__ __launch_bounds__(512, 4) void gat_main(
    const unsigned* __restrict__ Abits, const unsigned short* __restrict__ HbfT,
    const float* __restrict__ es_g, const float* __restrict__ es2_g,
    const float* __restrict__ ed_g, const float* __restrict__ ed2_g,
    float* __restrict__ Hacc, float* __restrict__ lpart)
{
    const int n0 = blockIdx.x * 128;     // row tile
    const int c0 = blockIdx.y * 256;     // col chunk
    const int hg = blockIdx.z;           // head group (heads hg*2, hg*2+1)
    const int tid  = threadIdx.x;
    const int w    = tid >> 6;           // wave 0..7 -> row subtile
    const int lane = tid & 63;
    const int r    = lane & 15;          // A row within subtile / C col
    const int q    = lane >> 4;          // quad

    __shared__ unsigned short Hlds[2][64][256];  // 64 KB, XOR-swizzled 16B blocks
    __shared__ unsigned bits_lds[128 * 9];       // 128 rows x 8 words, stride 9

    // ---- stage H chunk: HbfT[h][o][c0..c0+256) -> Hlds[hl][o][.], swizzled ----
    #pragma unroll
    for (int it = 0; it < 8; ++it) {
        int flat = it * 512 + tid;               // 0..4095 (16B blocks)
        int rowc = flat >> 5;                    // hl*64+o
        int c16  = flat & 31;
        int o    = rowc & 63, hl2 = rowc >> 6;
        int blk  = c16 ^ (o & 31);
        *(bf16x8*)&Hlds[hl2][o][blk * 8] =
            *(const bf16x8*)&HbfT[((size_t)(hg * 2 + hl2) * FOUT + o) * NN + c0 + c16 * 8];
    }
    // ---- stage adjacency bits: 128 rows x 8 u32 ----
    #pragma unroll
    for (int it = 0; it < 2; ++it) {
        int flat = it * 512 + tid;               // 0..1023
        int row = flat >> 3, wd = flat & 7;
        bits_lds[row * 9 + wd] = Abits[(size_t)(n0 + row) * 128 + (c0 >> 5) + wd];
    }
    __syncthreads();

    bf16x8 ones;
    #pragma unroll
    for (int i = 0; i < 8; ++i) ones[i] = (short)0x3F80;   // bf16 1.0

    const int bits_base = (w * 16 + r) * 9;
    const int qs = q * 8;

    for (int hl = 0; hl < 2; ++hl) {
        const int h  = hg * 2 + hl;
        const int n  = n0 + w * 16 + r;
        const float es  = es_g [h * NN + n];
        const float es2 = es2_g[h * NN + n];
        const float* edh  = ed_g  + h * NN + c0;
        const float* ed2h = ed2_g + h * NN + c0;

        f32x4 acc0 = {0,0,0,0}, acc1 = {0,0,0,0}, acc2 = {0,0,0,0},
              acc3 = {0,0,0,0}, accl = {0,0,0,0};

        #pragma unroll
        for (int step = 0; step < 8; ++step) {
            const unsigned bits32 = bits_lds[bits_base + step];
            const int mk = step * 32 + qs;

            const float4 e0 = *(const float4*)&edh [mk];
            const float4 e1 = *(const float4*)&edh [mk + 4];
            const float4 g0 = *(const float4*)&ed2h[mk];
            const float4 g1 = *(const float4*)&ed2h[mk + 4];
            const float edv [8] = {e0.x, e0.y, e0.z, e0.w, e1.x, e1.y, e1.z, e1.w};
            const float ed2v[8] = {g0.x, g0.y, g0.z, g0.w, g1.x, g1.y, g1.z, g1.w};

            u32x4 afu;
            #pragma unroll
            for (int p = 0; p < 4; ++p) {
                const int j0 = 2 * p, j1 = 2 * p + 1;
                float wa = ((bits32 >> (qs + j0)) & 1u)
                         ? fmaxf(es * edv[j0], es2 * ed2v[j0]) : 0.0f;
                float wb = ((bits32 >> (qs + j1)) & 1u)
                         ? fmaxf(es * edv[j1], es2 * ed2v[j1]) : 0.0f;
                afu[p] = (unsigned)f32_bf16(wa) | ((unsigned)f32_bf16(wb) << 16);
            }
            const bf16x8 af = __builtin_bit_cast(bf16x8, afu);

            // B fragments from swizzled LDS
            const int mb = step * 4 + q;         // 16B-block index
            const bf16x8 b0 = *(const bf16x8*)&Hlds[hl][r     ][(mb ^ ((r     ) & 31)) * 8];
            const bf16x8 b1 = *(const bf16x8*)&Hlds[hl][r + 16][(mb ^ ((r + 16) & 31)) * 8];
            const bf16x8 b2 = *(const bf16x8*)&Hlds[hl][r + 32][(mb ^ ((r + 32) & 31)) * 8];
            const bf16x8 b3 = *(const bf16x8*)&Hlds[hl][r + 48][(mb ^ ((r + 48) & 31)) * 8];

            acc0 = __builtin_amdgcn_mfma_f32_16x16x32_bf16(af, b0,   acc0, 0, 0, 0);
            acc1 = __builtin_amdgcn_mfma_f32_16x16x32_bf16(af, b1,   acc1, 0, 0, 0);
            acc2 = __builtin_amdgcn_mfma_f32_16x16x32_bf16(af, b2,   acc2, 0, 0, 0);
            acc3 = __builtin_amdgcn_mfma_f32_16x16x32_bf16(af, b3,   acc3, 0, 0, 0);
            accl = __builtin_amdgcn_mfma_f32_16x16x32_bf16(af, ones, accl, 0, 0, 0);
        }

        // ---- epilogue: unnormalized partial accumulation (K-split) ----
        float* hb = Hacc + ((size_t)h * NN + n0 + w * 16) * FOUT;
        #pragma unroll
        for (int reg = 0; reg < 4; ++reg) {
            const int rr = q * 4 + reg;
            atomicAdd(&hb[rr * FOUT +  0 + r], acc0[reg]);
            atomicAdd(&hb[rr * FOUT + 16 + r], acc1[reg]);
            atomicAdd(&hb[rr * FOUT + 32 + r], acc2[reg]);
            atomicAdd(&hb[rr * FOUT + 48 + r], acc3[reg]);
        }
        if (r == 0) {                     // col 0 lanes hold row-sums
            #pragma unroll
            for (int reg = 0; reg < 4; ++reg)
                atomicAdd(&lpart[h * NN + n0 + w * 16 + q * 4 + reg], accl[reg]);
        }
    }
}

// ---------------- Kernel 3: finalize ----------------
// out[n][o] = sum_h (Hacc[h][n][o] + w_diag*Hrow[h][n][o]) * 0.25/(l[h][n]+w_diag)
__global__ __launch_bounds__(256) void gat_fin(
    const float* __restrict__ Hacc, const float* __restrict__ Hrow,
    const float* __restrict__ lpart, const float* __restrict__ s_g,
    const float* __restrict__ d_g, float* __restrict__ out)
{
    const int tid = threadIdx.x;
    const int rr  = tid >> 4;
    const int c4  = tid & 15;
    const int n   = blockIdx.x * 16 + rr;
    const int o   = c4 * 4;

    float4 res = make_float4(0.f, 0.f, 0.f, 0.f);
    #pragma unroll
    for (int h = 0; h < NH; ++h) {
        float l  = lpart[h * NN + n];
        float tt = s_g[h * NN + n] + d_g[h * NN + n];
        float wd = __expf(fmaxf(tt, 0.01f * tt));
        float inv = 0.25f / (l + wd);
        float4 ha = *(const float4*)&Hacc[((size_t)h * NN + n) * FOUT + o];
        float4 hr = *(const float4*)&Hrow[((size_t)h * NN + n) * FOUT + o];
        res.x += (ha.x + wd * hr.x) * inv;
        res.y += (ha.y + wd * hr.y) * inv;
        res.z += (ha.z + wd * hr.z) * inv;
        res.w += (ha.w + wd * hr.w) * inv;
    }
    *(float4*)&out[(size_t)n * FOUT + o] = res;
}

extern "C" void kernel_launch(void* const* d_in, const int* in_sizes, int n_in,
                              void* d_out, int out_size, void* d_ws, size_t ws_size,
                              hipStream_t stream) {
    const float* X   = (const float*)d_in[0];
    const int*   A   = (const int*)  d_in[1];
    const float* W   = (const float*)d_in[2];
    const float* b   = (const float*)d_in[3];
    const float* att = (const float*)d_in[4];
    float* out = (float*)d_out;

    char* ws = (char*)d_ws;
    unsigned short* HbfT = (unsigned short*)ws;                    // 2 MB
    size_t off = (size_t)NH * FOUT * NN * 2;
    float* s_buf = (float*)(ws + off);  off += (size_t)NH * NN * 4;        // 64 KB
    float* d_buf = (float*)(ws + off);  off += (size_t)NH * NN * 4;        // 64 KB
    float* Hacc  = (float*)(ws + off);  off += (size_t)NH * NN * FOUT * 4; // 4 MB
    float* lpart = (float*)(ws + off);  off += (size_t)NH * NN * 4;        // 64 KB
    float* Hrow  = (float*)(ws + off);  off += (size_t)NH * NN * FOUT * 4; // 4 MB
    unsigned long long* Abits = (unsigned long long*)(ws + off);
    off += (size_t)NN * 64 * 8;                                            // 2 MB
    float* es_buf  = (float*)(ws + off); off += (size_t)NH * NN * 4;
    float* es2_buf = (float*)(ws + off); off += (size_t)NH * NN * 4;
    float* ed_buf  = (float*)(ws + off); off += (size_t)NH * NN * 4;
    float* ed2_buf = (float*)(ws + off); off += (size_t)NH * NN * 4;

    const int n4 = (NH * NN * FOUT + NH * NN) / 4;     // zero Hacc+lpart (contiguous)
    zero_f4<<<(n4 + 255) / 256, 256, 0, stream>>>((float4*)Hacc, n4);
    pack_bits<<<NN * 16, 256, 0, stream>>>(A, Abits);
    gat_prep<<<dim3(128, 4), 256, 0, stream>>>(X, W, b, att, HbfT, Hrow, s_buf, d_buf,
                                               es_buf, es2_buf, ed_buf, ed2_buf);
    gat_main<<<dim3(32, 16, 2), 512, 0, stream>>>((const unsigned*)Abits, HbfT,
                                                  es_buf, es2_buf, ed_buf, ed2_buf,
                                                  Hacc, lpart);
    gat_fin<<<256, 256, 0, stream>>>(Hacc, Hrow, lpart, s_buf, d_buf, out);
}